// Round 1
// baseline (2736.078 us; speedup 1.0000x reference)
//
#include <hip/hip_runtime.h>

typedef __bf16 bf16_t;
typedef __bf16 bf16x8 __attribute__((ext_vector_type(8)));
typedef __bf16 bf16x4 __attribute__((ext_vector_type(4)));
typedef float f32x4 __attribute__((ext_vector_type(4)));

#define B_ 4
#define N_ 2048
#define D_ 1024
#define H_ 8
#define NB_ 4
#define M_ (B_*N_)      // 8192 rows
#define QN_ 3072        // pruned qkv output cols: q(1024) k(1024) v(1024)

// ---------------- workspace layout (bytes) ----------------
// Assumes ws_size >= ~118 MB.
static constexpr size_t WT_OFF  = 0;                               // bf16 (NB,3072,1024)
static constexpr size_t WT_SZ   = (size_t)NB_*QN_*D_*2;
static constexpr size_t OWT_OFF = WT_OFF + WT_SZ;                  // bf16 (NB,1024,1024)
static constexpr size_t OWT_SZ  = (size_t)NB_*D_*D_*2;
static constexpr size_t XN_OFF  = OWT_OFF + OWT_SZ;                // bf16 (8192,1024)
static constexpr size_t XN_SZ   = (size_t)M_*D_*2;
static constexpr size_t QKV_OFF = XN_OFF + XN_SZ;                  // bf16 (8192,3072)
static constexpr size_t QKV_SZ  = (size_t)M_*QN_*2;
static constexpr size_t ATT_OFF = QKV_OFF + QKV_SZ;                // bf16 (8192,1024)
static constexpr size_t ATT_SZ  = (size_t)M_*D_*2;
static constexpr size_t QBR_OFF = ATT_OFF + ATT_SZ;                // f32 (NB,3072)
static constexpr size_t QBR_SZ  = (size_t)NB_*QN_*4;
static constexpr size_t VS_OFF  = QBR_OFF + QBR_SZ;                // f32 (32,128)

// ---------------- weight repack: qkv_w (NB,1024,4096) -> WT (NB,3072,1024) bf16, transposed, pruned ----------------
__global__ __launch_bounds__(256) void repack_qkvw(const float* __restrict__ qw, bf16_t* __restrict__ wt)
{
    __shared__ float tile[64][65];
    const int nb = blockIdx.z;
    const int j0 = blockIdx.x * 64, d0 = blockIdx.y * 64;
    const int tx = threadIdx.x, ty = threadIdx.y;
    const float* src = qw + (size_t)nb * D_ * 4096;
    const int jj = j0 + tx;
    const int sel = jj >> 10, rr = jj & 1023, hh = rr >> 7, aa = rr & 127;
    const int orig = hh * 512 + sel * 128 + aa;   // q:[0,128) k:[128,256) v:[256,384) per head
#pragma unroll
    for (int it = 0; it < 16; ++it) {
        int dr = it * 4 + ty;
        tile[dr][tx] = src[(size_t)(d0 + dr) * 4096 + orig];
    }
    __syncthreads();
    bf16_t* dst = wt + (size_t)nb * QN_ * D_;
#pragma unroll
    for (int it = 0; it < 16; ++it) {
        int jr = it * 4 + ty;
        dst[(size_t)(j0 + jr) * D_ + d0 + tx] = (bf16_t)tile[tx][jr];
    }
}

// out_w (NB,1024,1024) -> OWT (NB,1024,1024) bf16 transposed: OWT[n][k] = out_w[k][n]
__global__ __launch_bounds__(256) void repack_outw(const float* __restrict__ ow, bf16_t* __restrict__ owt)
{
    __shared__ float tile[64][65];
    const int nb = blockIdx.z;
    const int j0 = blockIdx.x * 64, d0 = blockIdx.y * 64;
    const int tx = threadIdx.x, ty = threadIdx.y;
    const float* src = ow + (size_t)nb * D_ * D_;
#pragma unroll
    for (int it = 0; it < 16; ++it) {
        int dr = it * 4 + ty;
        tile[dr][tx] = src[(size_t)(d0 + dr) * D_ + j0 + tx];
    }
    __syncthreads();
    bf16_t* dst = owt + (size_t)nb * D_ * D_;
#pragma unroll
    for (int it = 0; it < 16; ++it) {
        int jr = it * 4 + ty;
        dst[(size_t)(j0 + jr) * D_ + d0 + tx] = (bf16_t)tile[tx][jr];
    }
}

__global__ __launch_bounds__(256) void repack_qb(const float* __restrict__ qb, float* __restrict__ qbr)
{
    int idx = blockIdx.x * 256 + threadIdx.x;   // < NB*3072
    int nb = idx / QN_, jj = idx % QN_;
    int sel = jj >> 10, rr = jj & 1023, hh = rr >> 7, aa = rr & 127;
    qbr[idx] = qb[nb * 4096 + hh * 512 + sel * 128 + aa];
}

// ---------------- LayerNorm: x fp32 (8192,1024) -> xn bf16 ----------------
__global__ __launch_bounds__(256) void ln_kernel(const float* __restrict__ x, const float* __restrict__ g,
                                                 const float* __restrict__ bb, bf16_t* __restrict__ xn)
{
    const int row = blockIdx.x, tid = threadIdx.x;
    const float4 v = ((const float4*)(x + (size_t)row * D_))[tid];
    float s = v.x + v.y + v.z + v.w;
    float q = v.x * v.x + v.y * v.y + v.z * v.z + v.w * v.w;
#pragma unroll
    for (int d = 32; d >= 1; d >>= 1) { s += __shfl_xor(s, d); q += __shfl_xor(q, d); }
    __shared__ float ls[4], lq[4];
    if ((tid & 63) == 0) { ls[tid >> 6] = s; lq[tid >> 6] = q; }
    __syncthreads();
    s = ls[0] + ls[1] + ls[2] + ls[3];
    q = lq[0] + lq[1] + lq[2] + lq[3];
    const float mean = s * (1.f / 1024.f);
    const float var  = q * (1.f / 1024.f) - mean * mean;
    const float inv  = rsqrtf(var + 1e-5f);
    const float4 gg = ((const float4*)g)[tid];
    const float4 bv = ((const float4*)bb)[tid];
    bf16x4 o;
    o[0] = (bf16_t)((v.x - mean) * inv * gg.x + bv.x);
    o[1] = (bf16_t)((v.y - mean) * inv * gg.y + bv.y);
    o[2] = (bf16_t)((v.z - mean) * inv * gg.z + bv.z);
    o[3] = (bf16_t)((v.w - mean) * inv * gg.w + bv.w);
    *(bf16x4*)(xn + (size_t)row * D_ + tid * 4) = o;
}

// ---------------- GEMM (NT): C = A(MxK) * BT(NxK)^T + bias; 128x128 tile, 4 waves ----------------
template<bool RESID>
__global__ __launch_bounds__(256) void gemm_nt(const bf16_t* __restrict__ Am, const bf16_t* __restrict__ Bt,
                                               const float* __restrict__ bias, float* __restrict__ resid_out,
                                               bf16_t* __restrict__ outH, int Kn, int Nn)
{
    __shared__ bf16_t As[128 * 32];
    __shared__ bf16_t Bs[128 * 32];
    const int tid = threadIdx.x;
    const int lane = tid & 63, wave = tid >> 6;
    const int quad = lane >> 4, l15 = lane & 15;
    const int m0 = blockIdx.y * 128, n0 = blockIdx.x * 128;
    const int mw = (wave >> 1) * 64, nw = (wave & 1) * 64;
    f32x4 acc[4][4] = {};
    const int row = tid >> 1, half = (tid & 1) * 16;
    const bf16_t* agp = Am + (size_t)(m0 + row) * Kn + half;
    const bf16_t* bgp = Bt + (size_t)(n0 + row) * Kn + half;
    for (int kb = 0; kb < Kn; kb += 32) {
        bf16x8 av0 = *(const bf16x8*)(agp);
        bf16x8 av1 = *(const bf16x8*)(agp + 8);
        bf16x8 bv0 = *(const bf16x8*)(bgp);
        bf16x8 bv1 = *(const bf16x8*)(bgp + 8);
        agp += 32; bgp += 32;
        *(bf16x8*)(&As[row * 32 + half]) = av0;
        *(bf16x8*)(&As[row * 32 + half + 8]) = av1;
        *(bf16x8*)(&Bs[row * 32 + half]) = bv0;
        *(bf16x8*)(&Bs[row * 32 + half + 8]) = bv1;
        __syncthreads();
        bf16x8 af[4], bfv[4];
#pragma unroll
        for (int i = 0; i < 4; i++) af[i] = *(const bf16x8*)(&As[(mw + i * 16 + l15) * 32 + quad * 8]);
#pragma unroll
        for (int j = 0; j < 4; j++) bfv[j] = *(const bf16x8*)(&Bs[(nw + j * 16 + l15) * 32 + quad * 8]);
#pragma unroll
        for (int i = 0; i < 4; i++)
#pragma unroll
            for (int j = 0; j < 4; j++)
                acc[i][j] = __builtin_amdgcn_mfma_f32_16x16x32_bf16(af[i], bfv[j], acc[i][j], 0, 0, 0);
        __syncthreads();
    }
#pragma unroll
    for (int i = 0; i < 4; i++) {
#pragma unroll
        for (int j = 0; j < 4; j++) {
            const int colg = n0 + nw + j * 16 + l15;
            const float bv = bias[colg];
#pragma unroll
            for (int r = 0; r < 4; r++) {
                const int rowg = m0 + mw + i * 16 + quad * 4 + r;
                const size_t off = (size_t)rowg * Nn + colg;
                const float v = acc[i][j][r] + bv;
                if (RESID) resid_out[off] += v;
                else       outH[off] = (bf16_t)v;
            }
        }
    }
}

// ---------------- vsum[bh][l] = sum_m v[b][m][h][l] (for fully-masked softmax rows) ----------------
__global__ __launch_bounds__(256) void vsum_kernel(const bf16_t* __restrict__ qkv, float* __restrict__ vs)
{
    const int bh = blockIdx.x, b = bh >> 3, h = bh & 7;
    const int tid = threadIdx.x, l = tid & 127, part = tid >> 7;
    const bf16_t* base = qkv + (size_t)b * N_ * QN_ + 2048 + h * 128 + l;
    float s = 0.f;
    for (int m = part * 1024; m < part * 1024 + 1024; ++m)
        s += (float)base[(size_t)m * QN_];
    __shared__ float tmp[256];
    tmp[tid] = s;
    __syncthreads();
    if (tid < 128) vs[bh * 128 + tid] = tmp[tid] + tmp[tid + 128];
}

// ---------------- fused masked-silu-softmax attention, flash-style over m-tiles ----------------
__global__ __launch_bounds__(256) void attn_kernel(const bf16_t* __restrict__ qkv, const int* __restrict__ past_ids,
                                                   const float* __restrict__ vsum, bf16_t* __restrict__ att)
{
    __shared__ bf16_t Qs[128 * 136];   // Q tile (n, a)
    __shared__ bf16_t KPs[128 * 136];  // K tile (m, a), later overwritten by P (n, m)
    __shared__ bf16_t Vs[128 * 140];   // V tile (m, l), natural layout
    __shared__ float den[128];
    __shared__ float vsr[128];
    __shared__ unsigned char validn[128], validm[128];

    const int bx = blockIdx.x;
    const int bh = bx & 31, t = bx >> 5;     // t-major dispatch: heavy tiles first
    const int b = bh >> 3, h = bh & 7;
    const int n0 = t << 7;
    const int tid = threadIdx.x, lane = tid & 63, wave = tid >> 6;
    const int quad = lane >> 4, l15 = lane & 15;
    const int mw = (wave >> 1) * 64, nw = (wave & 1) * 64;
    const size_t basern = (size_t)b * N_ * QN_;

    {   // load Q tile
        int c = tid;
#pragma unroll
        for (int it = 0; it < 8; ++it, c += 256) {
            const int r = c >> 4, cc = (c & 15) * 8;
            bf16x8 v = *(const bf16x8*)(qkv + basern + (size_t)(n0 + r) * QN_ + h * 128 + cc);
            *(bf16x8*)(&Qs[r * 136 + cc]) = v;
        }
    }
    if (tid < 128) {
        validn[tid] = past_ids[b * N_ + n0 + tid] != 0;
        den[tid] = 0.f;
        vsr[tid] = vsum[bh * 128 + tid];
    }
    f32x4 oacc[4][4] = {};
    __syncthreads();

    const float scaleA = 0.08838834764831845f;   // 1/sqrt(128)
    const float invN = 1.f / 2048.f;

    for (int mt = t; mt < 16; ++mt) {
        const int m0 = mt << 7;
        {   // stage K (vector) and V (vector, natural layout)
            int c = tid;
#pragma unroll
            for (int it = 0; it < 8; ++it, c += 256) {
                const int r = c >> 4, cc = (c & 15) * 8;
                bf16x8 kv = *(const bf16x8*)(qkv + basern + (size_t)(m0 + r) * QN_ + 1024 + h * 128 + cc);
                *(bf16x8*)(&KPs[r * 136 + cc]) = kv;
                bf16x8 vv = *(const bf16x8*)(qkv + basern + (size_t)(m0 + r) * QN_ + 2048 + h * 128 + cc);
                bf16x4 lo = __builtin_shufflevector(vv, vv, 0, 1, 2, 3);
                bf16x4 hi = __builtin_shufflevector(vv, vv, 4, 5, 6, 7);
                *(bf16x4*)(&Vs[r * 140 + cc]) = lo;
                *(bf16x4*)(&Vs[r * 140 + cc + 4]) = hi;
            }
        }
        if (tid < 128) validm[tid] = past_ids[b * N_ + m0 + tid] != 0;
        __syncthreads();

        // S = Q K^T  (rows n in mw quadrant, cols m in nw quadrant)
        f32x4 sacc[4][4] = {};
#pragma unroll
        for (int kk = 0; kk < 4; ++kk) {
            bf16x8 af[4], bfv[4];
#pragma unroll
            for (int i = 0; i < 4; i++) af[i] = *(const bf16x8*)(&Qs[(mw + i * 16 + l15) * 136 + kk * 32 + quad * 8]);
#pragma unroll
            for (int j = 0; j < 4; j++) bfv[j] = *(const bf16x8*)(&KPs[(nw + j * 16 + l15) * 136 + kk * 32 + quad * 8]);
#pragma unroll
            for (int i = 0; i < 4; i++)
#pragma unroll
                for (int j = 0; j < 4; j++)
                    sacc[i][j] = __builtin_amdgcn_mfma_f32_16x16x32_bf16(af[i], bfv[j], sacc[i][j], 0, 0, 0);
        }
        __syncthreads();   // everyone done reading K before overwrite with P

        // logits -> e; write P into KPs; accumulate row sums
        float rsum[4][4] = {};
#pragma unroll
        for (int i = 0; i < 4; i++) {
#pragma unroll
            for (int j = 0; j < 4; j++) {
#pragma unroll
                for (int r = 0; r < 4; r++) {
                    const int rl = mw + i * 16 + quad * 4 + r;   // local n
                    const int cl = nw + j * 16 + l15;            // local m
                    const int gn = n0 + rl, gm = m0 + cl;
                    float e = 0.f;
                    if (gm > gn && validm[cl] && validn[rl]) {
                        const float sv = sacc[i][j][r] * scaleA;
                        const float sil = sv * __builtin_amdgcn_rcpf(1.f + __expf(-sv));
                        e = __expf(sil * invN);
                    }
                    const bf16_t eb = (bf16_t)e;
                    KPs[rl * 136 + cl] = eb;
                    rsum[i][r] += (float)eb;
                }
            }
        }
#pragma unroll
        for (int i = 0; i < 4; i++)
#pragma unroll
            for (int r = 0; r < 4; r++) {
                float v = rsum[i][r];
                v += __shfl_xor(v, 1); v += __shfl_xor(v, 2);
                v += __shfl_xor(v, 4); v += __shfl_xor(v, 8);
                if (l15 == 0) atomicAdd(&den[mw + i * 16 + quad * 4 + r], v);
            }
        __syncthreads();   // P complete

        // O += P V   (K-dim = m; B-frags gathered from natural-layout Vs)
#pragma unroll
        for (int kk = 0; kk < 4; ++kk) {
            bf16x8 af[4], bfv[4];
#pragma unroll
            for (int i = 0; i < 4; i++) af[i] = *(const bf16x8*)(&KPs[(mw + i * 16 + l15) * 136 + kk * 32 + quad * 8]);
#pragma unroll
            for (int j = 0; j < 4; j++) {
                bf16x8 bv;
#pragma unroll
                for (int jj = 0; jj < 8; jj++)
                    bv[jj] = Vs[(kk * 32 + quad * 8 + jj) * 140 + nw + j * 16 + l15];
                bfv[j] = bv;
            }
#pragma unroll
            for (int i = 0; i < 4; i++)
#pragma unroll
                for (int j = 0; j < 4; j++)
                    oacc[i][j] = __builtin_amdgcn_mfma_f32_16x16x32_bf16(af[i], bfv[j], oacc[i][j], 0, 0, 0);
        }
        __syncthreads();   // PV reads done before next staging overwrites
    }

    // epilogue: normalize (den==0 -> uniform softmax = vsum/N), write attn (b,n,h*128+l)
#pragma unroll
    for (int i = 0; i < 4; i++) {
#pragma unroll
        for (int r = 0; r < 4; r++) {
            const int rl = mw + i * 16 + quad * 4 + r;
            const float dn = den[rl];
            const bool uni = !(dn > 0.f);
            const float rc = uni ? 0.f : __builtin_amdgcn_rcpf(dn);
            const int gn = n0 + rl;
#pragma unroll
            for (int j = 0; j < 4; j++) {
                const int cl = nw + j * 16 + l15;
                const float ov = uni ? (vsr[cl] * invN) : (oacc[i][j][r] * rc);
                att[(size_t)(b * N_ + gn) * 1024 + h * 128 + cl] = (bf16_t)ov;
            }
        }
    }
}

extern "C" void kernel_launch(void* const* d_in, const int* in_sizes, int n_in,
                              void* d_out, int out_size, void* d_ws, size_t ws_size,
                              hipStream_t stream) {
    (void)in_sizes; (void)n_in; (void)out_size; (void)ws_size;
    const int*   past_ids = (const int*)d_in[1];
    const float* past_emb = (const float*)d_in[2];
    const float* qkv_w    = (const float*)d_in[3];
    const float* qkv_b    = (const float*)d_in[4];
    const float* out_w    = (const float*)d_in[5];
    const float* out_b    = (const float*)d_in[6];
    const float* ln_g     = (const float*)d_in[7];
    const float* ln_b     = (const float*)d_in[8];

    float* x = (float*)d_out;
    char* ws = (char*)d_ws;
    bf16_t* WT  = (bf16_t*)(ws + WT_OFF);
    bf16_t* OWT = (bf16_t*)(ws + OWT_OFF);
    bf16_t* XN  = (bf16_t*)(ws + XN_OFF);
    bf16_t* QKV = (bf16_t*)(ws + QKV_OFF);
    bf16_t* ATT = (bf16_t*)(ws + ATT_OFF);
    float*  QBR = (float*)(ws + QBR_OFF);
    float*  VS  = (float*)(ws + VS_OFF);

    hipMemcpyAsync(x, past_emb, (size_t)M_ * D_ * sizeof(float), hipMemcpyDeviceToDevice, stream);
    repack_qkvw<<<dim3(48, 16, NB_), dim3(64, 4), 0, stream>>>(qkv_w, WT);
    repack_outw<<<dim3(16, 16, NB_), dim3(64, 4), 0, stream>>>(out_w, OWT);
    repack_qb<<<48, 256, 0, stream>>>(qkv_b, QBR);

    for (int layer = 0; layer < NB_; ++layer) {
        ln_kernel<<<M_, 256, 0, stream>>>(x, ln_g + layer * D_, ln_b + layer * D_, XN);
        gemm_nt<false><<<dim3(QN_ / 128, M_ / 128), 256, 0, stream>>>(
            XN, WT + (size_t)layer * QN_ * D_, QBR + layer * QN_, nullptr, QKV, D_, QN_);
        vsum_kernel<<<32, 256, 0, stream>>>(QKV, VS);
        attn_kernel<<<512, 256, 0, stream>>>(QKV, past_ids, VS, ATT);
        gemm_nt<true><<<dim3(D_ / 128, M_ / 128), 256, 0, stream>>>(
            ATT, OWT + (size_t)layer * D_ * D_, out_b + layer * D_, x, nullptr, D_, D_);
    }
}

// Round 2
// 1193.336 us; speedup vs baseline: 2.2928x; 2.2928x over previous
//
#include <hip/hip_runtime.h>

typedef __bf16 bf16_t;
typedef __bf16 bf16x8 __attribute__((ext_vector_type(8)));
typedef __bf16 bf16x4 __attribute__((ext_vector_type(4)));
typedef float f32x4 __attribute__((ext_vector_type(4)));

#define B_ 4
#define N_ 2048
#define D_ 1024
#define H_ 8
#define NB_ 4
#define M_ (B_*N_)      // 8192 rows
#define QN_ 3072        // pruned qkv output cols: q(1024) k(1024) v(1024)

__device__ __forceinline__ void async_copy16(const void* gsrc, void* ldst) {
    __builtin_amdgcn_global_load_lds(
        (const __attribute__((address_space(1))) void*)gsrc,
        (__attribute__((address_space(3))) void*)ldst, 16, 0, 0);
}

// ---------------- workspace layout (bytes) ----------------
static constexpr size_t WT_OFF  = 0;                               // bf16 (NB,3072,1024)
static constexpr size_t WT_SZ   = (size_t)NB_*QN_*D_*2;
static constexpr size_t OWT_OFF = WT_OFF + WT_SZ;                  // bf16 (NB,1024,1024)
static constexpr size_t OWT_SZ  = (size_t)NB_*D_*D_*2;
static constexpr size_t XN_OFF  = OWT_OFF + OWT_SZ;                // bf16 (8192,1024)
static constexpr size_t XN_SZ   = (size_t)M_*D_*2;
static constexpr size_t QKV_OFF = XN_OFF + XN_SZ;                  // bf16 (8192,3072)
static constexpr size_t QKV_SZ  = (size_t)M_*QN_*2;
static constexpr size_t ATT_OFF = QKV_OFF + QKV_SZ;                // bf16 (8192,1024)
static constexpr size_t ATT_SZ  = (size_t)M_*D_*2;
static constexpr size_t QBR_OFF = ATT_OFF + ATT_SZ;                // f32 (NB,3072)
static constexpr size_t QBR_SZ  = (size_t)NB_*QN_*4;
static constexpr size_t VS_OFF  = QBR_OFF + QBR_SZ;                // f32 (32,128)

// ---------------- weight repack: qkv_w (NB,1024,4096) -> WT (NB,3072,1024) bf16, transposed, pruned ----------------
__global__ __launch_bounds__(256) void repack_qkvw(const float* __restrict__ qw, bf16_t* __restrict__ wt)
{
    __shared__ float tile[64][65];
    const int nb = blockIdx.z;
    const int j0 = blockIdx.x * 64, d0 = blockIdx.y * 64;
    const int tx = threadIdx.x, ty = threadIdx.y;
    const float* src = qw + (size_t)nb * D_ * 4096;
    const int jj = j0 + tx;
    const int sel = jj >> 10, rr = jj & 1023, hh = rr >> 7, aa = rr & 127;
    const int orig = hh * 512 + sel * 128 + aa;   // q:[0,128) k:[128,256) v:[256,384) per head
#pragma unroll
    for (int it = 0; it < 16; ++it) {
        int dr = it * 4 + ty;
        tile[dr][tx] = src[(size_t)(d0 + dr) * 4096 + orig];
    }
    __syncthreads();
    bf16_t* dst = wt + (size_t)nb * QN_ * D_;
#pragma unroll
    for (int it = 0; it < 16; ++it) {
        int jr = it * 4 + ty;
        dst[(size_t)(j0 + jr) * D_ + d0 + tx] = (bf16_t)tile[tx][jr];
    }
}

// out_w (NB,1024,1024) -> OWT transposed
__global__ __launch_bounds__(256) void repack_outw(const float* __restrict__ ow, bf16_t* __restrict__ owt)
{
    __shared__ float tile[64][65];
    const int nb = blockIdx.z;
    const int j0 = blockIdx.x * 64, d0 = blockIdx.y * 64;
    const int tx = threadIdx.x, ty = threadIdx.y;
    const float* src = ow + (size_t)nb * D_ * D_;
#pragma unroll
    for (int it = 0; it < 16; ++it) {
        int dr = it * 4 + ty;
        tile[dr][tx] = src[(size_t)(d0 + dr) * D_ + j0 + tx];
    }
    __syncthreads();
    bf16_t* dst = owt + (size_t)nb * D_ * D_;
#pragma unroll
    for (int it = 0; it < 16; ++it) {
        int jr = it * 4 + ty;
        dst[(size_t)(j0 + jr) * D_ + d0 + tx] = (bf16_t)tile[tx][jr];
    }
}

__global__ __launch_bounds__(256) void repack_qb(const float* __restrict__ qb, float* __restrict__ qbr)
{
    int idx = blockIdx.x * 256 + threadIdx.x;   // < NB*3072
    int nb = idx / QN_, jj = idx % QN_;
    int sel = jj >> 10, rr = jj & 1023, hh = rr >> 7, aa = rr & 127;
    qbr[idx] = qb[nb * 4096 + hh * 512 + sel * 128 + aa];
}

// ---------------- LayerNorm: x fp32 (8192,1024) -> xn bf16 ----------------
__global__ __launch_bounds__(256) void ln_kernel(const float* __restrict__ x, const float* __restrict__ g,
                                                 const float* __restrict__ bb, bf16_t* __restrict__ xn)
{
    const int row = blockIdx.x, tid = threadIdx.x;
    const float4 v = ((const float4*)(x + (size_t)row * D_))[tid];
    float s = v.x + v.y + v.z + v.w;
    float q = v.x * v.x + v.y * v.y + v.z * v.z + v.w * v.w;
#pragma unroll
    for (int d = 32; d >= 1; d >>= 1) { s += __shfl_xor(s, d); q += __shfl_xor(q, d); }
    __shared__ float ls[4], lq[4];
    if ((tid & 63) == 0) { ls[tid >> 6] = s; lq[tid >> 6] = q; }
    __syncthreads();
    s = ls[0] + ls[1] + ls[2] + ls[3];
    q = lq[0] + lq[1] + lq[2] + lq[3];
    const float mean = s * (1.f / 1024.f);
    const float var  = q * (1.f / 1024.f) - mean * mean;
    const float inv  = rsqrtf(var + 1e-5f);
    const float4 gg = ((const float4*)g)[tid];
    const float4 bv = ((const float4*)bb)[tid];
    bf16x4 o;
    o[0] = (bf16_t)((v.x - mean) * inv * gg.x + bv.x);
    o[1] = (bf16_t)((v.y - mean) * inv * gg.y + bv.y);
    o[2] = (bf16_t)((v.z - mean) * inv * gg.z + bv.z);
    o[3] = (bf16_t)((v.w - mean) * inv * gg.w + bv.w);
    *(bf16x4*)(xn + (size_t)row * D_ + tid * 4) = o;
}

// ---------------- GEMM (NT), m97-style: global_load_lds width-16 staging ----------------
template<bool RESID>
__global__ __launch_bounds__(256) void gemm_nt(const bf16_t* __restrict__ Am, const bf16_t* __restrict__ Bt,
                                               const float* __restrict__ bias, float* __restrict__ resid_out,
                                               bf16_t* __restrict__ outH, int Kn, int Nn)
{
    __shared__ bf16_t As[128 * 32];
    __shared__ bf16_t Bs[128 * 32];
    const int tid = threadIdx.x;
    const int lane = tid & 63, wave = tid >> 6;
    const int quad = lane >> 4, l15 = lane & 15;
    const int m0 = blockIdx.y * 128, n0 = blockIdx.x * 128;
    const int mw = (wave >> 1) * 64, nw = (wave & 1) * 64;
    const int ch0 = wave * 2, ch1 = ch0 + 1;
    const int lrow = lane >> 2, lcol = (lane & 3) * 8;
    const bf16_t* ga0 = Am + (size_t)(m0 + ch0 * 16 + lrow) * Kn + lcol;
    const bf16_t* ga1 = Am + (size_t)(m0 + ch1 * 16 + lrow) * Kn + lcol;
    const bf16_t* gb0 = Bt + (size_t)(n0 + ch0 * 16 + lrow) * Kn + lcol;
    const bf16_t* gb1 = Bt + (size_t)(n0 + ch1 * 16 + lrow) * Kn + lcol;
    bf16_t* la0 = &As[ch0 * 512]; bf16_t* la1 = &As[ch1 * 512];
    bf16_t* lb0 = &Bs[ch0 * 512]; bf16_t* lb1 = &Bs[ch1 * 512];
    f32x4 acc[4][4] = {};
    for (int kb = 0; kb < Kn; kb += 32) {
        async_copy16(ga0, la0); async_copy16(ga1, la1);
        async_copy16(gb0, lb0); async_copy16(gb1, lb1);
        ga0 += 32; ga1 += 32; gb0 += 32; gb1 += 32;
        __syncthreads();
        bf16x8 af[4], bfv[4];
#pragma unroll
        for (int i = 0; i < 4; i++) af[i] = *(const bf16x8*)(&As[(mw + i * 16 + l15) * 32 + quad * 8]);
#pragma unroll
        for (int j = 0; j < 4; j++) bfv[j] = *(const bf16x8*)(&Bs[(nw + j * 16 + l15) * 32 + quad * 8]);
#pragma unroll
        for (int i = 0; i < 4; i++)
#pragma unroll
            for (int j = 0; j < 4; j++)
                acc[i][j] = __builtin_amdgcn_mfma_f32_16x16x32_bf16(af[i], bfv[j], acc[i][j], 0, 0, 0);
        __syncthreads();
    }
#pragma unroll
    for (int i = 0; i < 4; i++) {
#pragma unroll
        for (int j = 0; j < 4; j++) {
            const int colg = n0 + nw + j * 16 + l15;
            const float bv = bias[colg];
#pragma unroll
            for (int r = 0; r < 4; r++) {
                const int rowg = m0 + mw + i * 16 + quad * 4 + r;
                const size_t off = (size_t)rowg * Nn + colg;
                const float v = acc[i][j][r] + bv;
                if (RESID) resid_out[off] += v;
                else       outH[off] = (bf16_t)v;
            }
        }
    }
}

// ---------------- vsum[bh][l] = sum_m v[b][m][h][l], coalesced; needs VS pre-zeroed ----------------
__global__ __launch_bounds__(256) void vsum_kernel(const bf16_t* __restrict__ qkv, float* __restrict__ vs)
{
    // grid 256: bh(32) x chunk(8), 256 rows per chunk
    const int blk = blockIdx.x;
    const int bh = blk >> 3, ck = blk & 7;
    const int b = bh >> 3, h = bh & 7;
    const int tid = threadIdx.x;
    const int rg = tid >> 4, c8 = (tid & 15) * 8;
    const bf16_t* base = qkv + (size_t)b * N_ * QN_ + 2048 + h * 128 + c8;
    float acc[8] = {};
    for (int m = ck * 256 + rg; m < ck * 256 + 256; m += 16) {
        bf16x8 v = *(const bf16x8*)(base + (size_t)m * QN_);
#pragma unroll
        for (int u = 0; u < 8; ++u) acc[u] += (float)v[u];
    }
    __shared__ float tmp[256 * 8];
#pragma unroll
    for (int u = 0; u < 8; ++u) tmp[tid * 8 + u] = acc[u];
    __syncthreads();
    if (tid < 128) {
        float s = 0.f;
#pragma unroll
        for (int g = 0; g < 16; ++g) s += tmp[(g * 16 + (tid >> 3)) * 8 + (tid & 7)];
        atomicAdd(&vs[bh * 128 + tid], s);
    }
}

// ---------------- fused masked-silu-softmax attention ----------------
// 64-row Q tile, 4 waves; wave w owns rows [16w,16w+16): softmax/P/PV wave-private.
// LDS ~69.8KB -> 2 blocks/CU. K staged via global_load_lds (chunked [kk][128][32]);
// V global-loads prefetched into VGPRs behind QK MFMAs, then written to padded natural layout.
__global__ __launch_bounds__(256) void attn_kernel(const bf16_t* __restrict__ qkv, const int* __restrict__ past_ids,
                                                   const float* __restrict__ vsum, bf16_t* __restrict__ att)
{
    __shared__ bf16_t Qs[4 * 64 * 32];     // [kk][row][32]  16KB
    __shared__ bf16_t KVs[128 * 140];      // K: [kk][128][32] (32KB) then V: [m][140] (35.8KB)
    __shared__ bf16_t Ps[64 * 136];        // wave-private P rows  17.4KB
    __shared__ unsigned char validm_s[128];

    const int bx = blockIdx.x;
    const int bh = bx & 31, t = bx >> 5;   // t-major: heavy (low-t) blocks dispatch first
    const int b = bh >> 3, h = bh & 7;
    const int n0 = t << 6;
    const int tid = threadIdx.x, lane = tid & 63, wave = tid >> 6;
    const int quad = lane >> 4, l15 = lane & 15;
    const int lrow = lane >> 2, lcol8 = (lane & 3) * 8;
    const size_t baseq = (size_t)b * N_ * QN_;
    const float scaleA = 0.08838834764831845f;   // 1/sqrt(128)
    const float invN = 1.f / 2048.f;

    // stage Q (async): 4 chunks/wave
    {
        const bf16_t* gq = qkv + baseq + (size_t)(n0 + wave * 16 + lrow) * QN_ + h * 128 + lcol8;
#pragma unroll
        for (int kk = 0; kk < 4; ++kk)
            async_copy16(gq + kk * 32, &Qs[kk * 2048 + wave * 512]);
    }
    int vnr[4];
#pragma unroll
    for (int r = 0; r < 4; ++r) vnr[r] = past_ids[b * N_ + n0 + wave * 16 + quad * 4 + r] != 0;

    f32x4 oacc[8] = {};
    float denacc[4] = {};

    for (int mt = (t >> 1); mt < 16; ++mt) {
        const int m0 = mt << 7;
        // stage K (async, chunked)
#pragma unroll
        for (int s = 0; s < 8; ++s) {
            const int kk = s & 3, rg = (s >> 2) + wave * 2;
            async_copy16(qkv + baseq + (size_t)(m0 + rg * 16 + lrow) * QN_ + 1024 + h * 128 + kk * 32 + lcol8,
                         &KVs[kk * 4096 + rg * 512]);
        }
        if (tid < 128) validm_s[tid] = past_ids[b * N_ + m0 + tid] != 0;
        __syncthreads();   // K + validm ready (drains vmcnt)

        // prefetch V into VGPRs (latency hides behind QK MFMAs)
        bf16x8 vpre[8];
#pragma unroll
        for (int p = 0; p < 8; ++p)
            vpre[p] = *(const bf16x8*)(qkv + baseq + (size_t)(m0 + p * 16 + (tid >> 4)) * QN_ + 2048 + h * 128 + (tid & 15) * 8);

        // S = Q K^T : wave rows [16w,16w+16) x 128 m-cols
        f32x4 sacc[8] = {};
#pragma unroll
        for (int kk = 0; kk < 4; ++kk) {
            bf16x8 qf = *(const bf16x8*)&Qs[kk * 2048 + (wave * 16 + l15) * 32 + quad * 8];
#pragma unroll
            for (int j = 0; j < 8; ++j) {
                bf16x8 kf = *(const bf16x8*)&KVs[kk * 4096 + (j * 16 + l15) * 32 + quad * 8];
                sacc[j] = __builtin_amdgcn_mfma_f32_16x16x32_bf16(qf, kf, sacc[j], 0, 0, 0);
            }
        }
        __syncthreads();   // all K reads done; KVs free for V

        // write V to padded natural layout
#pragma unroll
        for (int p = 0; p < 8; ++p) {
            const int row = p * 16 + (tid >> 4), c8 = (tid & 15) * 8;
            bf16x4 lo = __builtin_shufflevector(vpre[p], vpre[p], 0, 1, 2, 3);
            bf16x4 hi = __builtin_shufflevector(vpre[p], vpre[p], 4, 5, 6, 7);
            *(bf16x4*)&KVs[row * 140 + c8] = lo;
            *(bf16x4*)&KVs[row * 140 + c8 + 4] = hi;
        }

        // softmax (wave-private): e = 1 + silu(s)*invN  (exact to bf16; |silu/N| < 1e-2)
        float rsum[4] = {};
#pragma unroll
        for (int j = 0; j < 8; ++j) {
            const int cl = j * 16 + l15;
            const int gm = m0 + cl;
            const bool vm = validm_s[cl] != 0;
#pragma unroll
            for (int r = 0; r < 4; ++r) {
                const int gn = n0 + wave * 16 + quad * 4 + r;
                float e = 0.f;
                if (gm > gn && vm && vnr[r]) {
                    const float sv = sacc[j][r] * scaleA;
                    const float sig = __builtin_amdgcn_rcpf(1.f + __expf(-sv));
                    e = fmaf(sv * sig, invN, 1.f);
                }
                const bf16_t eb = (bf16_t)e;
                Ps[(wave * 16 + quad * 4 + r) * 136 + cl] = eb;
                rsum[r] += (float)eb;
            }
        }
#pragma unroll
        for (int r = 0; r < 4; ++r) {
            float v = rsum[r];
            v += __shfl_xor(v, 1); v += __shfl_xor(v, 2);
            v += __shfl_xor(v, 4); v += __shfl_xor(v, 8);
            denacc[r] += v;
        }
        __syncthreads();   // V staged complete

        // O += P V (A-frag = own P rows, vector; B-frag gathered from natural V, ~2-way banks)
#pragma unroll
        for (int kk = 0; kk < 4; ++kk) {
            bf16x8 pf = *(const bf16x8*)&Ps[(wave * 16 + l15) * 136 + kk * 32 + quad * 8];
#pragma unroll
            for (int j = 0; j < 8; ++j) {
                bf16x8 bv;
#pragma unroll
                for (int jj = 0; jj < 8; ++jj)
                    bv[jj] = KVs[(kk * 32 + quad * 8 + jj) * 140 + j * 16 + l15];
                oacc[j] = __builtin_amdgcn_mfma_f32_16x16x32_bf16(pf, bv, oacc[j], 0, 0, 0);
            }
        }
        __syncthreads();   // PV reads done before next K staging
    }

    // epilogue
#pragma unroll
    for (int r = 0; r < 4; ++r) {
        const int rl = wave * 16 + quad * 4 + r;
        const int gn = n0 + rl;
        const float dn = denacc[r];
        const bool uni = !(dn > 0.f);
        const float rc = uni ? 0.f : __builtin_amdgcn_rcpf(dn);
#pragma unroll
        for (int j = 0; j < 8; ++j) {
            const int col = j * 16 + l15;
            const float ov = uni ? (vsum[bh * 128 + col] * invN) : (oacc[j][r] * rc);
            att[(size_t)(b * N_ + gn) * 1024 + h * 128 + col] = (bf16_t)ov;
        }
    }
}

extern "C" void kernel_launch(void* const* d_in, const int* in_sizes, int n_in,
                              void* d_out, int out_size, void* d_ws, size_t ws_size,
                              hipStream_t stream) {
    (void)in_sizes; (void)n_in; (void)out_size; (void)ws_size;
    const int*   past_ids = (const int*)d_in[1];
    const float* past_emb = (const float*)d_in[2];
    const float* qkv_w    = (const float*)d_in[3];
    const float* qkv_b    = (const float*)d_in[4];
    const float* out_w    = (const float*)d_in[5];
    const float* out_b    = (const float*)d_in[6];
    const float* ln_g     = (const float*)d_in[7];
    const float* ln_b     = (const float*)d_in[8];

    float* x = (float*)d_out;
    char* ws = (char*)d_ws;
    bf16_t* WT  = (bf16_t*)(ws + WT_OFF);
    bf16_t* OWT = (bf16_t*)(ws + OWT_OFF);
    bf16_t* XN  = (bf16_t*)(ws + XN_OFF);
    bf16_t* QKV = (bf16_t*)(ws + QKV_OFF);
    bf16_t* ATT = (bf16_t*)(ws + ATT_OFF);
    float*  QBR = (float*)(ws + QBR_OFF);
    float*  VS  = (float*)(ws + VS_OFF);

    hipMemcpyAsync(x, past_emb, (size_t)M_ * D_ * sizeof(float), hipMemcpyDeviceToDevice, stream);
    repack_qkvw<<<dim3(48, 16, NB_), dim3(64, 4), 0, stream>>>(qkv_w, WT);
    repack_outw<<<dim3(16, 16, NB_), dim3(64, 4), 0, stream>>>(out_w, OWT);
    repack_qb<<<48, 256, 0, stream>>>(qkv_b, QBR);

    for (int layer = 0; layer < NB_; ++layer) {
        ln_kernel<<<M_, 256, 0, stream>>>(x, ln_g + layer * D_, ln_b + layer * D_, XN);
        gemm_nt<false><<<dim3(QN_ / 128, M_ / 128), 256, 0, stream>>>(
            XN, WT + (size_t)layer * QN_ * D_, QBR + layer * QN_, nullptr, QKV, D_, QN_);
        hipMemsetAsync(VS, 0, 32 * 128 * sizeof(float), stream);
        vsum_kernel<<<256, 256, 0, stream>>>(QKV, VS);
        attn_kernel<<<1024, 256, 0, stream>>>(QKV, past_ids, VS, ATT);
        gemm_nt<true><<<dim3(D_ / 128, M_ / 128), 256, 0, stream>>>(
            ATT, OWT + (size_t)layer * D_ * D_, out_b + layer * D_, x, nullptr, D_, D_);
    }
}

// Round 3
// 1143.014 us; speedup vs baseline: 2.3937x; 1.0440x over previous
//
#include <hip/hip_runtime.h>

typedef __bf16 bf16_t;
typedef __bf16 bf16x8 __attribute__((ext_vector_type(8)));
typedef __bf16 bf16x4 __attribute__((ext_vector_type(4)));
typedef float f32x4 __attribute__((ext_vector_type(4)));

#define B_ 4
#define N_ 2048
#define D_ 1024
#define H_ 8
#define NB_ 4
#define M_ (B_*N_)      // 8192 rows
#define QN_ 3072        // pruned qkv cols: q(1024) k(1024) v(1024)
#define QKN_ 2048       // q,k packed row stride

__device__ __forceinline__ void async_copy16(const void* gsrc, void* ldst) {
    __builtin_amdgcn_global_load_lds(
        (const __attribute__((address_space(1))) void*)gsrc,
        (__attribute__((address_space(3))) void*)ldst, 16, 0, 0);
}

// ---------------- workspace layout (bytes) ----------------
static constexpr size_t WT_OFF  = 0;                               // bf16 (NB,3072,1024)
static constexpr size_t WT_SZ   = (size_t)NB_*QN_*D_*2;
static constexpr size_t OWT_OFF = WT_OFF + WT_SZ;                  // bf16 (NB,1024,1024)
static constexpr size_t OWT_SZ  = (size_t)NB_*D_*D_*2;
static constexpr size_t XN_OFF  = OWT_OFF + OWT_SZ;                // bf16 (8192,1024)
static constexpr size_t XN_SZ   = (size_t)M_*D_*2;
static constexpr size_t QK_OFF  = XN_OFF + XN_SZ;                  // bf16 (8192,2048)  q|k
static constexpr size_t QK_SZ   = (size_t)M_*QKN_*2;
static constexpr size_t VT_OFF  = QK_OFF + QK_SZ;                  // bf16 (32,128,2048) v transposed
static constexpr size_t VT_SZ   = (size_t)32*128*N_*2;
static constexpr size_t ATT_OFF = VT_OFF + VT_SZ;                  // bf16 (8192,1024)
static constexpr size_t ATT_SZ  = (size_t)M_*D_*2;
static constexpr size_t QBR_OFF = ATT_OFF + ATT_SZ;                // f32 (NB,3072)
static constexpr size_t QBR_SZ  = (size_t)NB_*QN_*4;
static constexpr size_t VS_OFF  = QBR_OFF + QBR_SZ;                // f32 (32,128)

// ---------------- weight repack: qkv_w (NB,1024,4096) -> WT (NB,3072,1024) bf16, transposed, pruned ----------------
__global__ __launch_bounds__(256) void repack_qkvw(const float* __restrict__ qw, bf16_t* __restrict__ wt)
{
    __shared__ float tile[64][65];
    const int nb = blockIdx.z;
    const int j0 = blockIdx.x * 64, d0 = blockIdx.y * 64;
    const int tx = threadIdx.x, ty = threadIdx.y;
    const float* src = qw + (size_t)nb * D_ * 4096;
    const int jj = j0 + tx;
    const int sel = jj >> 10, rr = jj & 1023, hh = rr >> 7, aa = rr & 127;
    const int orig = hh * 512 + sel * 128 + aa;   // q:[0,128) k:[128,256) v:[256,384) per head
#pragma unroll
    for (int it = 0; it < 16; ++it) {
        int dr = it * 4 + ty;
        tile[dr][tx] = src[(size_t)(d0 + dr) * 4096 + orig];
    }
    __syncthreads();
    bf16_t* dst = wt + (size_t)nb * QN_ * D_;
#pragma unroll
    for (int it = 0; it < 16; ++it) {
        int jr = it * 4 + ty;
        dst[(size_t)(j0 + jr) * D_ + d0 + tx] = (bf16_t)tile[tx][jr];
    }
}

__global__ __launch_bounds__(256) void repack_outw(const float* __restrict__ ow, bf16_t* __restrict__ owt)
{
    __shared__ float tile[64][65];
    const int nb = blockIdx.z;
    const int j0 = blockIdx.x * 64, d0 = blockIdx.y * 64;
    const int tx = threadIdx.x, ty = threadIdx.y;
    const float* src = ow + (size_t)nb * D_ * D_;
#pragma unroll
    for (int it = 0; it < 16; ++it) {
        int dr = it * 4 + ty;
        tile[dr][tx] = src[(size_t)(d0 + dr) * D_ + j0 + tx];
    }
    __syncthreads();
    bf16_t* dst = owt + (size_t)nb * D_ * D_;
#pragma unroll
    for (int it = 0; it < 16; ++it) {
        int jr = it * 4 + ty;
        dst[(size_t)(j0 + jr) * D_ + d0 + tx] = (bf16_t)tile[tx][jr];
    }
}

__global__ __launch_bounds__(256) void repack_qb(const float* __restrict__ qb, float* __restrict__ qbr)
{
    int idx = blockIdx.x * 256 + threadIdx.x;   // < NB*3072
    int nb = idx / QN_, jj = idx % QN_;
    int sel = jj >> 10, rr = jj & 1023, hh = rr >> 7, aa = rr & 127;
    qbr[idx] = qb[nb * 4096 + hh * 512 + sel * 128 + aa];
}

// ---------------- LayerNorm: x fp32 (8192,1024) -> xn bf16 ----------------
__global__ __launch_bounds__(256) void ln_kernel(const float* __restrict__ x, const float* __restrict__ g,
                                                 const float* __restrict__ bb, bf16_t* __restrict__ xn)
{
    const int row = blockIdx.x, tid = threadIdx.x;
    const float4 v = ((const float4*)(x + (size_t)row * D_))[tid];
    float s = v.x + v.y + v.z + v.w;
    float q = v.x * v.x + v.y * v.y + v.z * v.z + v.w * v.w;
#pragma unroll
    for (int d = 32; d >= 1; d >>= 1) { s += __shfl_xor(s, d); q += __shfl_xor(q, d); }
    __shared__ float ls[4], lq[4];
    if ((tid & 63) == 0) { ls[tid >> 6] = s; lq[tid >> 6] = q; }
    __syncthreads();
    s = ls[0] + ls[1] + ls[2] + ls[3];
    q = lq[0] + lq[1] + lq[2] + lq[3];
    const float mean = s * (1.f / 1024.f);
    const float var  = q * (1.f / 1024.f) - mean * mean;
    const float inv  = rsqrtf(var + 1e-5f);
    const float4 gg = ((const float4*)g)[tid];
    const float4 bv = ((const float4*)bb)[tid];
    bf16x4 o;
    o[0] = (bf16_t)((v.x - mean) * inv * gg.x + bv.x);
    o[1] = (bf16_t)((v.y - mean) * inv * gg.y + bv.y);
    o[2] = (bf16_t)((v.z - mean) * inv * gg.z + bv.z);
    o[3] = (bf16_t)((v.w - mean) * inv * gg.w + bv.w);
    *(bf16x4*)(xn + (size_t)row * D_ + tid * 4) = o;
}

// ---------------- GEMM (NT), m97-style staging. Columns >= vSplit (V block) go transposed to vtOut ----------------
template<bool RESID>
__global__ __launch_bounds__(256) void gemm_nt(const bf16_t* __restrict__ Am, const bf16_t* __restrict__ Bt,
                                               const float* __restrict__ bias, float* __restrict__ resid_out,
                                               bf16_t* __restrict__ outH, bf16_t* __restrict__ vtOut,
                                               int Kn, int Nn, int vSplit)
{
    __shared__ bf16_t As[128 * 32];
    __shared__ bf16_t Bs[128 * 32];
    const int tid = threadIdx.x;
    const int lane = tid & 63, wave = tid >> 6;
    const int quad = lane >> 4, l15 = lane & 15;
    const int m0 = blockIdx.y * 128, n0 = blockIdx.x * 128;
    const int mw = (wave >> 1) * 64, nw = (wave & 1) * 64;
    const int ch0 = wave * 2, ch1 = ch0 + 1;
    const int lrow = lane >> 2, lcol = (lane & 3) * 8;
    const bf16_t* ga0 = Am + (size_t)(m0 + ch0 * 16 + lrow) * Kn + lcol;
    const bf16_t* ga1 = Am + (size_t)(m0 + ch1 * 16 + lrow) * Kn + lcol;
    const bf16_t* gb0 = Bt + (size_t)(n0 + ch0 * 16 + lrow) * Kn + lcol;
    const bf16_t* gb1 = Bt + (size_t)(n0 + ch1 * 16 + lrow) * Kn + lcol;
    bf16_t* la0 = &As[ch0 * 512]; bf16_t* la1 = &As[ch1 * 512];
    bf16_t* lb0 = &Bs[ch0 * 512]; bf16_t* lb1 = &Bs[ch1 * 512];
    f32x4 acc[4][4] = {};
    for (int kb = 0; kb < Kn; kb += 32) {
        async_copy16(ga0, la0); async_copy16(ga1, la1);
        async_copy16(gb0, lb0); async_copy16(gb1, lb1);
        ga0 += 32; ga1 += 32; gb0 += 32; gb1 += 32;
        __syncthreads();
        bf16x8 af[4], bfv[4];
#pragma unroll
        for (int i = 0; i < 4; i++) af[i] = *(const bf16x8*)(&As[(mw + i * 16 + l15) * 32 + quad * 8]);
#pragma unroll
        for (int j = 0; j < 4; j++) bfv[j] = *(const bf16x8*)(&Bs[(nw + j * 16 + l15) * 32 + quad * 8]);
#pragma unroll
        for (int i = 0; i < 4; i++)
#pragma unroll
            for (int j = 0; j < 4; j++)
                acc[i][j] = __builtin_amdgcn_mfma_f32_16x16x32_bf16(af[i], bfv[j], acc[i][j], 0, 0, 0);
        __syncthreads();
    }
    if (!RESID && n0 >= vSplit) {
        // V block: write transposed VT[(b*8+h)*128 + l][m]
#pragma unroll
        for (int i = 0; i < 4; i++) {
            const int rowg = m0 + mw + i * 16 + quad * 4;      // r=0 row; 4 consecutive
            const int bb2 = rowg >> 11, mloc = rowg & 2047;
#pragma unroll
            for (int j = 0; j < 4; j++) {
                const int colg = n0 + nw + j * 16 + l15;
                const int hh = (colg - 2048) >> 7, ll = (colg - 2048) & 127;
                const float bv = bias[colg];
                bf16x4 sv;
#pragma unroll
                for (int r = 0; r < 4; r++) sv[r] = (bf16_t)(acc[i][j][r] + bv);
                *(bf16x4*)(vtOut + ((size_t)(bb2 * 8 + hh) * 128 + ll) * (size_t)N_ + mloc) = sv;
            }
        }
        return;
    }
#pragma unroll
    for (int i = 0; i < 4; i++) {
#pragma unroll
        for (int j = 0; j < 4; j++) {
            const int colg = n0 + nw + j * 16 + l15;
            const float bv = bias[colg];
#pragma unroll
            for (int r = 0; r < 4; r++) {
                const int rowg = m0 + mw + i * 16 + quad * 4 + r;
                const size_t off = (size_t)rowg * Nn + colg;
                const float v = acc[i][j][r] + bv;
                if (RESID) resid_out[off] += v;
                else       outH[off] = (bf16_t)v;
            }
        }
    }
}

// ---------------- vsum[row] = sum_m VT[row][m];  row = bh*128 + l ----------------
__global__ __launch_bounds__(256) void vsum_kernel(const bf16_t* __restrict__ vt, float* __restrict__ vs)
{
    const int gid = blockIdx.x * 4 + (threadIdx.x >> 6);   // 0..4095
    const int lane = threadIdx.x & 63;
    const bf16_t* p = vt + (size_t)gid * N_ + lane * 8;
    float s = 0.f;
#pragma unroll
    for (int c = 0; c < 4; ++c) {
        bf16x8 v = *(const bf16x8*)(p + c * 512);
#pragma unroll
        for (int u = 0; u < 8; ++u) s += (float)v[u];
    }
#pragma unroll
    for (int d = 32; d >= 1; d >>= 1) s += __shfl_xor(s, d);
    if (lane == 0) vs[gid] = s;
}

// ---------------- fused masked-silu-softmax attention ----------------
// 64-row Q tile, 4 waves, wave owns 16 rows. All LDS->reg traffic vectorized (b128).
// Ks buffer holds K during QK, then Vt (pre-transposed global VT) during PV.
// LDS = 16K(Q) + 32K(K/Vt) + 16K(P) + 128B = 65.7KB -> 2 blocks/CU.
__global__ __launch_bounds__(256, 2) void attn_kernel(const bf16_t* __restrict__ qk, const bf16_t* __restrict__ vt,
                                                      const int* __restrict__ past_ids, const float* __restrict__ vsum,
                                                      bf16_t* __restrict__ att)
{
    __shared__ bf16_t Qs[4 * 64 * 32];     // [kk][qrow][32]
    __shared__ bf16_t Ks[4 * 128 * 32];    // [kk][row][32]: K rows=m, then Vt rows=l
    __shared__ bf16_t Ps[4 * 64 * 32];     // [kk][qrow][32] chunked P
    __shared__ unsigned char validm_s[128];

    const int bx = blockIdx.x;
    const int bh = bx & 31, t = bx >> 5;   // t-major: heavy (low-t) blocks first
    const int b = bh >> 3, h = bh & 7;
    const int n0 = t << 6;
    const int tid = threadIdx.x, lane = tid & 63, wave = tid >> 6;
    const int quad = lane >> 4, l15 = lane & 15;
    const int lrow = lane >> 2, lcol8 = (lane & 3) * 8;
    const size_t baseq = (size_t)b * N_ * QKN_;
    const bf16_t* vtb = vt + (size_t)bh * 128 * N_;
    const float scaleA = 0.08838834764831845f;   // 1/sqrt(128)
    const float invN = 1.f / 2048.f;

    // stage Q (async): 4 chunks/wave
    {
        const bf16_t* gq = qk + baseq + (size_t)(n0 + wave * 16 + lrow) * QKN_ + h * 128 + lcol8;
#pragma unroll
        for (int kk = 0; kk < 4; ++kk)
            async_copy16(gq + kk * 32, &Qs[kk * 2048 + wave * 512 + lane * 8]);
    }
    int vnr[4];
#pragma unroll
    for (int r = 0; r < 4; ++r) vnr[r] = past_ids[b * N_ + n0 + wave * 16 + quad * 4 + r] != 0;

    f32x4 oacc[8] = {};
    float denacc[4] = {};

    for (int mt = (t >> 1); mt < 16; ++mt) {
        const int m0 = mt << 7;
        __syncthreads();   // prev PV reads done before Ks overwrite
        // stage K (async, chunked)
#pragma unroll
        for (int s = 0; s < 8; ++s) {
            const int kk = s & 3, rg = (s >> 2) + wave * 2;
            async_copy16(qk + baseq + (size_t)(m0 + rg * 16 + lrow) * QKN_ + 1024 + h * 128 + kk * 32 + lcol8,
                         &Ks[kk * 4096 + rg * 512 + lane * 8]);
        }
        if (tid < 128) validm_s[tid] = past_ids[b * N_ + m0 + tid] != 0;
        __syncthreads();   // K + validm ready

        // S = Q K^T : wave rows [16w,16w+16) x 128 m-cols
        f32x4 sacc[8] = {};
#pragma unroll
        for (int kk = 0; kk < 4; ++kk) {
            bf16x8 qf = *(const bf16x8*)&Qs[kk * 2048 + (wave * 16 + l15) * 32 + quad * 8];
#pragma unroll
            for (int j = 0; j < 8; ++j) {
                bf16x8 kf = *(const bf16x8*)&Ks[kk * 4096 + (j * 16 + l15) * 32 + quad * 8];
                sacc[j] = __builtin_amdgcn_mfma_f32_16x16x32_bf16(qf, kf, sacc[j], 0, 0, 0);
            }
        }
        __syncthreads();   // all K reads done; Ks free for Vt

        // stage Vt into Ks (latency hides behind softmax)
#pragma unroll
        for (int s = 0; s < 8; ++s) {
            const int kk = s & 3, rg = (s >> 2) + wave * 2;
            async_copy16(vtb + (size_t)(rg * 16 + lrow) * N_ + m0 + kk * 32 + lcol8,
                         &Ks[kk * 4096 + rg * 512 + lane * 8]);
        }

        // softmax (wave-private): e = 1 + silu(s)/N
        const bool full = (m0 > n0 + 63);
        float rsum[4] = {};
#pragma unroll
        for (int j = 0; j < 8; ++j) {
            const int cl = j * 16 + l15;
            const int gm = m0 + cl;
            const bool vm = validm_s[cl] != 0;
#pragma unroll
            for (int r = 0; r < 4; ++r) {
                const int gn = n0 + wave * 16 + quad * 4 + r;
                float e = 0.f;
                if ((full || gm > gn) && vm && vnr[r]) {
                    const float sv = sacc[j][r] * scaleA;
                    const float sig = __builtin_amdgcn_rcpf(1.f + __expf(-sv));
                    e = fmaf(sv * sig, invN, 1.f);
                }
                const bf16_t eb = (bf16_t)e;
                Ps[(cl >> 5) * 2048 + (wave * 16 + quad * 4 + r) * 32 + (cl & 31)] = eb;
                rsum[r] += (float)eb;
            }
        }
#pragma unroll
        for (int r = 0; r < 4; ++r) {
            float v = rsum[r];
            v += __shfl_xor(v, 1); v += __shfl_xor(v, 2);
            v += __shfl_xor(v, 4); v += __shfl_xor(v, 8);
            denacc[r] += v;
        }
        __syncthreads();   // Vt staged (barrier drains vmcnt); P wave-private (lgkm ordering)

        // O += P Vt : A = own P rows (vector), B = Vt frags (vector)
#pragma unroll
        for (int kk = 0; kk < 4; ++kk) {
            bf16x8 pf = *(const bf16x8*)&Ps[kk * 2048 + (wave * 16 + l15) * 32 + quad * 8];
#pragma unroll
            for (int j = 0; j < 8; ++j) {
                bf16x8 vf = *(const bf16x8*)&Ks[kk * 4096 + (j * 16 + l15) * 32 + quad * 8];
                oacc[j] = __builtin_amdgcn_mfma_f32_16x16x32_bf16(pf, vf, oacc[j], 0, 0, 0);
            }
        }
    }

    // epilogue
#pragma unroll
    for (int r = 0; r < 4; ++r) {
        const int rl = wave * 16 + quad * 4 + r;
        const int gn = n0 + rl;
        const float dn = denacc[r];
        const bool uni = !(dn > 0.f);
        const float rc = uni ? 0.f : __builtin_amdgcn_rcpf(dn);
#pragma unroll
        for (int j = 0; j < 8; ++j) {
            const int col = j * 16 + l15;
            const float ov = uni ? (vsum[bh * 128 + col] * invN) : (oacc[j][r] * rc);
            att[(size_t)(b * N_ + gn) * 1024 + h * 128 + col] = (bf16_t)ov;
        }
    }
}

extern "C" void kernel_launch(void* const* d_in, const int* in_sizes, int n_in,
                              void* d_out, int out_size, void* d_ws, size_t ws_size,
                              hipStream_t stream) {
    (void)in_sizes; (void)n_in; (void)out_size; (void)ws_size;
    const int*   past_ids = (const int*)d_in[1];
    const float* past_emb = (const float*)d_in[2];
    const float* qkv_w    = (const float*)d_in[3];
    const float* qkv_b    = (const float*)d_in[4];
    const float* out_w    = (const float*)d_in[5];
    const float* out_b    = (const float*)d_in[6];
    const float* ln_g     = (const float*)d_in[7];
    const float* ln_b     = (const float*)d_in[8];

    float* x = (float*)d_out;
    char* ws = (char*)d_ws;
    bf16_t* WT  = (bf16_t*)(ws + WT_OFF);
    bf16_t* OWT = (bf16_t*)(ws + OWT_OFF);
    bf16_t* XN  = (bf16_t*)(ws + XN_OFF);
    bf16_t* QK  = (bf16_t*)(ws + QK_OFF);
    bf16_t* VT  = (bf16_t*)(ws + VT_OFF);
    bf16_t* ATT = (bf16_t*)(ws + ATT_OFF);
    float*  QBR = (float*)(ws + QBR_OFF);
    float*  VS  = (float*)(ws + VS_OFF);

    hipMemcpyAsync(x, past_emb, (size_t)M_ * D_ * sizeof(float), hipMemcpyDeviceToDevice, stream);
    repack_qkvw<<<dim3(48, 16, NB_), dim3(64, 4), 0, stream>>>(qkv_w, WT);
    repack_outw<<<dim3(16, 16, NB_), dim3(64, 4), 0, stream>>>(out_w, OWT);
    repack_qb<<<48, 256, 0, stream>>>(qkv_b, QBR);

    for (int layer = 0; layer < NB_; ++layer) {
        ln_kernel<<<M_, 256, 0, stream>>>(x, ln_g + layer * D_, ln_b + layer * D_, XN);
        gemm_nt<false><<<dim3(QN_ / 128, M_ / 128), 256, 0, stream>>>(
            XN, WT + (size_t)layer * QN_ * D_, QBR + layer * QN_, nullptr, QK, VT, D_, QKN_, 2048);
        vsum_kernel<<<1024, 256, 0, stream>>>(VT, VS);
        attn_kernel<<<1024, 256, 0, stream>>>(QK, VT, past_ids, VS, ATT);
        gemm_nt<true><<<dim3(D_ / 128, M_ / 128), 256, 0, stream>>>(
            ATT, OWT + (size_t)layer * D_ * D_, out_b + layer * D_, x, nullptr, nullptr, D_, D_, 1 << 30);
    }
}

// Round 4
// 980.405 us; speedup vs baseline: 2.7908x; 1.1659x over previous
//
#include <hip/hip_runtime.h>

typedef __bf16 bf16_t;
typedef __bf16 bf16x8 __attribute__((ext_vector_type(8)));
typedef __bf16 bf16x4 __attribute__((ext_vector_type(4)));
typedef float f32x4 __attribute__((ext_vector_type(4)));

#define B_ 4
#define N_ 2048
#define D_ 1024
#define H_ 8
#define NB_ 4
#define M_ (B_*N_)      // 8192 rows
#define QN_ 3072        // pruned qkv cols: q(1024) k(1024) v(1024)
#define QKN_ 2048       // q,k packed row stride

__device__ __forceinline__ void async_copy16(const void* gsrc, void* ldst) {
    __builtin_amdgcn_global_load_lds(
        (const __attribute__((address_space(1))) void*)gsrc,
        (__attribute__((address_space(3))) void*)ldst, 16, 0, 0);
}

// ---------------- workspace layout (bytes) ----------------
static constexpr size_t WT_OFF  = 0;                               // bf16 (NB,3072,1024)
static constexpr size_t WT_SZ   = (size_t)NB_*QN_*D_*2;
static constexpr size_t OWT_OFF = WT_OFF + WT_SZ;                  // bf16 (NB,1024,1024)
static constexpr size_t OWT_SZ  = (size_t)NB_*D_*D_*2;
static constexpr size_t XN_OFF  = OWT_OFF + OWT_SZ;                // bf16 (8192,1024)
static constexpr size_t XN_SZ   = (size_t)M_*D_*2;
static constexpr size_t QK_OFF  = XN_OFF + XN_SZ;                  // bf16 (8192,2048)  q|k
static constexpr size_t QK_SZ   = (size_t)M_*QKN_*2;
static constexpr size_t VT_OFF  = QK_OFF + QK_SZ;                  // bf16 (32,128,2048) v transposed
static constexpr size_t VT_SZ   = (size_t)32*128*N_*2;
static constexpr size_t ATT_OFF = VT_OFF + VT_SZ;                  // bf16 (8192,1024)
static constexpr size_t ATT_SZ  = (size_t)M_*D_*2;
static constexpr size_t QBR_OFF = ATT_OFF + ATT_SZ;                // f32 (NB,3072)
static constexpr size_t QBR_SZ  = (size_t)NB_*QN_*4;
static constexpr size_t VS_OFF  = QBR_OFF + QBR_SZ;                // f32 (32,128)

// ---------------- weight repack: qkv_w (NB,1024,4096) -> WT (NB,3072,1024) bf16, transposed, pruned ----------------
__global__ __launch_bounds__(256) void repack_qkvw(const float* __restrict__ qw, bf16_t* __restrict__ wt)
{
    __shared__ float tile[64][65];
    const int nb = blockIdx.z;
    const int j0 = blockIdx.x * 64, d0 = blockIdx.y * 64;
    const int tx = threadIdx.x, ty = threadIdx.y;
    const float* src = qw + (size_t)nb * D_ * 4096;
    const int jj = j0 + tx;
    const int sel = jj >> 10, rr = jj & 1023, hh = rr >> 7, aa = rr & 127;
    const int orig = hh * 512 + sel * 128 + aa;   // q:[0,128) k:[128,256) v:[256,384) per head
#pragma unroll
    for (int it = 0; it < 16; ++it) {
        int dr = it * 4 + ty;
        tile[dr][tx] = src[(size_t)(d0 + dr) * 4096 + orig];
    }
    __syncthreads();
    bf16_t* dst = wt + (size_t)nb * QN_ * D_;
#pragma unroll
    for (int it = 0; it < 16; ++it) {
        int jr = it * 4 + ty;
        dst[(size_t)(j0 + jr) * D_ + d0 + tx] = (bf16_t)tile[tx][jr];
    }
}

__global__ __launch_bounds__(256) void repack_outw(const float* __restrict__ ow, bf16_t* __restrict__ owt)
{
    __shared__ float tile[64][65];
    const int nb = blockIdx.z;
    const int j0 = blockIdx.x * 64, d0 = blockIdx.y * 64;
    const int tx = threadIdx.x, ty = threadIdx.y;
    const float* src = ow + (size_t)nb * D_ * D_;
#pragma unroll
    for (int it = 0; it < 16; ++it) {
        int dr = it * 4 + ty;
        tile[dr][tx] = src[(size_t)(d0 + dr) * D_ + j0 + tx];
    }
    __syncthreads();
    bf16_t* dst = owt + (size_t)nb * D_ * D_;
#pragma unroll
    for (int it = 0; it < 16; ++it) {
        int jr = it * 4 + ty;
        dst[(size_t)(j0 + jr) * D_ + d0 + tx] = (bf16_t)tile[tx][jr];
    }
}

__global__ __launch_bounds__(256) void repack_qb(const float* __restrict__ qb, float* __restrict__ qbr)
{
    int idx = blockIdx.x * 256 + threadIdx.x;   // < NB*3072
    int nb = idx / QN_, jj = idx % QN_;
    int sel = jj >> 10, rr = jj & 1023, hh = rr >> 7, aa = rr & 127;
    qbr[idx] = qb[nb * 4096 + hh * 512 + sel * 128 + aa];
}

// ---------------- LayerNorm: x fp32 (8192,1024) -> xn bf16 ----------------
__global__ __launch_bounds__(256) void ln_kernel(const float* __restrict__ x, const float* __restrict__ g,
                                                 const float* __restrict__ bb, bf16_t* __restrict__ xn)
{
    const int row = blockIdx.x, tid = threadIdx.x;
    const float4 v = ((const float4*)(x + (size_t)row * D_))[tid];
    float s = v.x + v.y + v.z + v.w;
    float q = v.x * v.x + v.y * v.y + v.z * v.z + v.w * v.w;
#pragma unroll
    for (int d = 32; d >= 1; d >>= 1) { s += __shfl_xor(s, d); q += __shfl_xor(q, d); }
    __shared__ float ls[4], lq[4];
    if ((tid & 63) == 0) { ls[tid >> 6] = s; lq[tid >> 6] = q; }
    __syncthreads();
    s = ls[0] + ls[1] + ls[2] + ls[3];
    q = lq[0] + lq[1] + lq[2] + lq[3];
    const float mean = s * (1.f / 1024.f);
    const float var  = q * (1.f / 1024.f) - mean * mean;
    const float inv  = rsqrtf(var + 1e-5f);
    const float4 gg = ((const float4*)g)[tid];
    const float4 bv = ((const float4*)bb)[tid];
    bf16x4 o;
    o[0] = (bf16_t)((v.x - mean) * inv * gg.x + bv.x);
    o[1] = (bf16_t)((v.y - mean) * inv * gg.y + bv.y);
    o[2] = (bf16_t)((v.z - mean) * inv * gg.z + bv.z);
    o[3] = (bf16_t)((v.w - mean) * inv * gg.w + bv.w);
    *(bf16x4*)(xn + (size_t)row * D_ + tid * 4) = o;
}

// ---------------- GEMM (NT), m97-style staging + XOR bank swizzle ----------------
template<bool RESID>
__global__ __launch_bounds__(256) void gemm_nt(const bf16_t* __restrict__ Am, const bf16_t* __restrict__ Bt,
                                               const float* __restrict__ bias, float* __restrict__ resid_out,
                                               bf16_t* __restrict__ outH, bf16_t* __restrict__ vtOut,
                                               int Kn, int Nn, int vSplit)
{
    __shared__ bf16_t As[128 * 32];
    __shared__ bf16_t Bs[128 * 32];
    const int tid = threadIdx.x;
    const int lane = tid & 63, wave = tid >> 6;
    const int quad = lane >> 4, l15 = lane & 15;
    const int swz = quad ^ ((l15 >> 1) & 3);                  // read-side chunk swizzle
    const int slane8 = ((lane & 3) ^ ((lane >> 3) & 3)) * 8;  // staging source col perm
    const int m0 = blockIdx.y * 128, n0 = blockIdx.x * 128;
    const int mw = (wave >> 1) * 64, nw = (wave & 1) * 64;
    const int ch0 = wave * 2, ch1 = ch0 + 1;
    const int lrow = lane >> 2;
    const bf16_t* ga0 = Am + (size_t)(m0 + ch0 * 16 + lrow) * Kn + slane8;
    const bf16_t* ga1 = Am + (size_t)(m0 + ch1 * 16 + lrow) * Kn + slane8;
    const bf16_t* gb0 = Bt + (size_t)(n0 + ch0 * 16 + lrow) * Kn + slane8;
    const bf16_t* gb1 = Bt + (size_t)(n0 + ch1 * 16 + lrow) * Kn + slane8;
    bf16_t* la0 = &As[ch0 * 512]; bf16_t* la1 = &As[ch1 * 512];
    bf16_t* lb0 = &Bs[ch0 * 512]; bf16_t* lb1 = &Bs[ch1 * 512];
    f32x4 acc[4][4] = {};
    for (int kb = 0; kb < Kn; kb += 32) {
        async_copy16(ga0, la0); async_copy16(ga1, la1);
        async_copy16(gb0, lb0); async_copy16(gb1, lb1);
        ga0 += 32; ga1 += 32; gb0 += 32; gb1 += 32;
        __syncthreads();
        bf16x8 af[4], bfv[4];
#pragma unroll
        for (int i = 0; i < 4; i++) af[i] = *(const bf16x8*)(&As[(mw + i * 16 + l15) * 32 + swz * 8]);
#pragma unroll
        for (int j = 0; j < 4; j++) bfv[j] = *(const bf16x8*)(&Bs[(nw + j * 16 + l15) * 32 + swz * 8]);
#pragma unroll
        for (int i = 0; i < 4; i++)
#pragma unroll
            for (int j = 0; j < 4; j++)
                acc[i][j] = __builtin_amdgcn_mfma_f32_16x16x32_bf16(af[i], bfv[j], acc[i][j], 0, 0, 0);
        __syncthreads();
    }
    if (!RESID && n0 >= vSplit) {
        // V block: write transposed VT[(b*8+h)*128 + l][m]
#pragma unroll
        for (int i = 0; i < 4; i++) {
            const int rowg = m0 + mw + i * 16 + quad * 4;      // r=0 row; 4 consecutive
            const int bb2 = rowg >> 11, mloc = rowg & 2047;
#pragma unroll
            for (int j = 0; j < 4; j++) {
                const int colg = n0 + nw + j * 16 + l15;
                const int hh = (colg - 2048) >> 7, ll = (colg - 2048) & 127;
                const float bv = bias[colg];
                bf16x4 sv;
#pragma unroll
                for (int r = 0; r < 4; r++) sv[r] = (bf16_t)(acc[i][j][r] + bv);
                *(bf16x4*)(vtOut + ((size_t)(bb2 * 8 + hh) * 128 + ll) * (size_t)N_ + mloc) = sv;
            }
        }
        return;
    }
#pragma unroll
    for (int i = 0; i < 4; i++) {
#pragma unroll
        for (int j = 0; j < 4; j++) {
            const int colg = n0 + nw + j * 16 + l15;
            const float bv = bias[colg];
#pragma unroll
            for (int r = 0; r < 4; r++) {
                const int rowg = m0 + mw + i * 16 + quad * 4 + r;
                const size_t off = (size_t)rowg * Nn + colg;
                const float v = acc[i][j][r] + bv;
                if (RESID) resid_out[off] += v;
                else       outH[off] = (bf16_t)v;
            }
        }
    }
}

// ---------------- vsum[row] = sum_m VT[row][m];  row = bh*128 + l ----------------
__global__ __launch_bounds__(256) void vsum_kernel(const bf16_t* __restrict__ vt, float* __restrict__ vs)
{
    const int gid = blockIdx.x * 4 + (threadIdx.x >> 6);   // 0..4095
    const int lane = threadIdx.x & 63;
    const bf16_t* p = vt + (size_t)gid * N_ + lane * 8;
    float s = 0.f;
#pragma unroll
    for (int c = 0; c < 4; ++c) {
        bf16x8 v = *(const bf16x8*)(p + c * 512);
#pragma unroll
        for (int u = 0; u < 8; ++u) s += (float)v[u];
    }
#pragma unroll
    for (int d = 32; d >= 1; d >>= 1) s += __shfl_xor(s, d);
    if (lane == 0) vs[gid] = s;
}

// ---------------- fused masked-silu-softmax attention (S^T formulation) ----------------
// 64-row Q tile, wave owns 16 n-rows; Q B-frags resident in VGPRs (no Q LDS).
// S^T = mfma(K, Q): lane holds 4 consecutive m per block -> P written as ds_write_b64.
// den via ones-MFMA. Sigmoid = clamped fma-quadratic (no transcendentals).
// LDS: K/Vt shared 32KB + P 16KB + vmf 512B = 48.5KB -> 3 blocks/CU.
template<bool CAUSAL>
__device__ __forceinline__ void attn_tile(
    int m0, int n0, int b, int h,
    const bf16_t* __restrict__ qk, const bf16_t* __restrict__ vtb,
    const int* __restrict__ past_ids,
    bf16_t* Ks, float* vmf, bf16_t* Ps,
    const bf16x8* qf, bf16x8 onesf, float vnf,
    f32x4* oacc, f32x4& dacc)
{
    const int tid = threadIdx.x, lane = tid & 63, wave = tid >> 6;
    const int quad = lane >> 4, l15 = lane & 15;
    const int swz = quad ^ ((l15 >> 1) & 3);
    const int slane8 = ((lane & 3) ^ ((lane >> 3) & 3)) * 8;
    const int lrow = lane >> 2;
    const size_t baseq = (size_t)b * N_ * QKN_;
    const float scaleA = 0.08838834764831845f;   // 1/sqrt(128)
    const float invN = 1.f / 2048.f;

    __syncthreads();   // prev PV reads done; Ks free
#pragma unroll
    for (int s = 0; s < 8; ++s) {
        const int kkc = s & 3, rg = (s >> 2) + wave * 2;
        async_copy16(qk + baseq + (size_t)(m0 + rg * 16 + lrow) * QKN_ + 1024 + h * 128 + kkc * 32 + slane8,
                     &Ks[kkc * 4096 + rg * 512 + lane * 8]);
    }
    if (tid < 128) vmf[tid] = past_ids[b * N_ + m0 + tid] != 0 ? 1.f : 0.f;
    __syncthreads();   // K + vmf ready

    // S^T = K Q^T : rows m (lane holds m = j*16+quad*4+r), col n16 = l15
    f32x4 sacc[8] = {};
#pragma unroll
    for (int kk = 0; kk < 4; ++kk) {
#pragma unroll
        for (int j = 0; j < 8; ++j) {
            bf16x8 kf = *(const bf16x8*)&Ks[kk * 4096 + (j * 16 + l15) * 32 + swz * 8];
            sacc[j] = __builtin_amdgcn_mfma_f32_16x16x32_bf16(kf, qf[kk], sacc[j], 0, 0, 0);
        }
    }
    __syncthreads();   // K reads done; Ks free for Vt

#pragma unroll
    for (int s = 0; s < 8; ++s) {
        const int kkc = s & 3, rg = (s >> 2) + wave * 2;
        async_copy16(vtb + (size_t)(rg * 16 + lrow) * N_ + m0 + kkc * 32 + slane8,
                     &Ks[kkc * 4096 + rg * 512 + lane * 8]);
    }

    // softmax (transcendental-free): e = mask * (1 + silu(s)/N)
    const int dbase = CAUSAL ? (m0 - n0 - wave * 16 - l15 + quad * 4) : 0;
#pragma unroll
    for (int j = 0; j < 8; ++j) {
        f32x4 mmv = *(const f32x4*)&vmf[j * 16 + quad * 4];   // broadcast read
        bf16x4 pv;
#pragma unroll
        for (int r = 0; r < 4; ++r) {
            const float sv = sacc[j][r] * scaleA;
            const float xc = fminf(fmaxf(sv, -4.f), 4.f);
            float sig = __builtin_fmaf(xc, 0.25f, 0.5f);           // quadratic sigmoid approx
            sig = __builtin_fmaf(-(xc * 0.03125f), fabsf(xc), sig);
            float e = __builtin_fmaf(sv * sig, invN, 1.f);
            e *= mmv[r] * vnf;
            if (CAUSAL) e = (dbase + j * 16 + r > 0) ? e : 0.f;
            pv[r] = (bf16_t)e;
        }
        const int cc = (j & 1) * 2 + (quad >> 1);
        const int cp = cc ^ ((l15 >> 1) & 3);
        *(bf16x4*)&Ps[wave * 2048 + (j >> 1) * 512 + l15 * 32 + cp * 8 + (quad & 1) * 4] = pv;
    }
    __syncthreads();   // Vt ready (vmcnt drained); P visible

    // O += P Vt ; den += P * ones
#pragma unroll
    for (int kk = 0; kk < 4; ++kk) {
        bf16x8 pf = *(const bf16x8*)&Ps[wave * 2048 + kk * 512 + l15 * 32 + swz * 8];
        dacc = __builtin_amdgcn_mfma_f32_16x16x32_bf16(pf, onesf, dacc, 0, 0, 0);
#pragma unroll
        for (int j = 0; j < 8; ++j) {
            bf16x8 vf = *(const bf16x8*)&Ks[kk * 4096 + (j * 16 + l15) * 32 + swz * 8];
            oacc[j] = __builtin_amdgcn_mfma_f32_16x16x32_bf16(pf, vf, oacc[j], 0, 0, 0);
        }
    }
}

__global__ __launch_bounds__(256, 3) void attn_kernel(const bf16_t* __restrict__ qk, const bf16_t* __restrict__ vt,
                                                      const int* __restrict__ past_ids, const float* __restrict__ vsum,
                                                      bf16_t* __restrict__ att)
{
    __shared__ bf16_t Ks[4 * 128 * 32];   // 32KB, K then Vt (swizzled chunks)
    __shared__ bf16_t Ps[4 * 2048];       // 16KB, per-wave P
    __shared__ float vmf[128];

    const int bx = blockIdx.x;
    const int bh = bx & 31, t = bx >> 5;   // t-major: heavy (low-t) blocks first
    const int b = bh >> 3, h = bh & 7;
    const int n0 = t << 6;
    const int tid = threadIdx.x, lane = tid & 63, wave = tid >> 6;
    const int quad = lane >> 4, l15 = lane & 15;
    const bf16_t* vtb = vt + (size_t)bh * 128 * N_;
    const float invN = 1.f / 2048.f;

    // Q B-frags resident in VGPRs (loaded once from global)
    bf16x8 qf[4];
    {
        const bf16_t* gq = qk + (size_t)b * N_ * QKN_ + (size_t)(n0 + wave * 16 + l15) * QKN_ + h * 128 + quad * 8;
#pragma unroll
        for (int kk = 0; kk < 4; ++kk) qf[kk] = *(const bf16x8*)(gq + kk * 32);
    }
    const float vnf = past_ids[b * N_ + n0 + wave * 16 + l15] != 0 ? 1.f : 0.f;
    bf16x8 onesf;
#pragma unroll
    for (int i = 0; i < 8; ++i) onesf[i] = (bf16_t)1.f;

    f32x4 oacc[8] = {};
    f32x4 dacc = {};

    const int mt0 = t >> 1;
    attn_tile<true>(mt0 << 7, n0, b, h, qk, vtb, past_ids, Ks, vmf, Ps, qf, onesf, vnf, oacc, dacc);
    for (int mt = mt0 + 1; mt < 16; ++mt)
        attn_tile<false>(mt << 7, n0, b, h, qk, vtb, past_ids, Ks, vmf, Ps, qf, onesf, vnf, oacc, dacc);

    // epilogue: rows n16 = quad*4+r, cols j*16+l15
    float vsr[8];
#pragma unroll
    for (int j = 0; j < 8; ++j) vsr[j] = vsum[bh * 128 + j * 16 + l15];
#pragma unroll
    for (int r = 0; r < 4; ++r) {
        const float dn = dacc[r];
        const bool uni = !(dn > 0.f);
        const float rc = uni ? 0.f : __builtin_amdgcn_rcpf(dn);
        const int gn = n0 + wave * 16 + quad * 4 + r;
#pragma unroll
        for (int j = 0; j < 8; ++j) {
            const int col = j * 16 + l15;
            const float ov = uni ? (vsr[j] * invN) : (oacc[j][r] * rc);
            att[(size_t)(b * N_ + gn) * 1024 + h * 128 + col] = (bf16_t)ov;
        }
    }
}

extern "C" void kernel_launch(void* const* d_in, const int* in_sizes, int n_in,
                              void* d_out, int out_size, void* d_ws, size_t ws_size,
                              hipStream_t stream) {
    (void)in_sizes; (void)n_in; (void)out_size; (void)ws_size;
    const int*   past_ids = (const int*)d_in[1];
    const float* past_emb = (const float*)d_in[2];
    const float* qkv_w    = (const float*)d_in[3];
    const float* qkv_b    = (const float*)d_in[4];
    const float* out_w    = (const float*)d_in[5];
    const float* out_b    = (const float*)d_in[6];
    const float* ln_g     = (const float*)d_in[7];
    const float* ln_b     = (const float*)d_in[8];

    float* x = (float*)d_out;
    char* ws = (char*)d_ws;
    bf16_t* WT  = (bf16_t*)(ws + WT_OFF);
    bf16_t* OWT = (bf16_t*)(ws + OWT_OFF);
    bf16_t* XN  = (bf16_t*)(ws + XN_OFF);
    bf16_t* QK  = (bf16_t*)(ws + QK_OFF);
    bf16_t* VT  = (bf16_t*)(ws + VT_OFF);
    bf16_t* ATT = (bf16_t*)(ws + ATT_OFF);
    float*  QBR = (float*)(ws + QBR_OFF);
    float*  VS  = (float*)(ws + VS_OFF);

    hipMemcpyAsync(x, past_emb, (size_t)M_ * D_ * sizeof(float), hipMemcpyDeviceToDevice, stream);
    repack_qkvw<<<dim3(48, 16, NB_), dim3(64, 4), 0, stream>>>(qkv_w, WT);
    repack_outw<<<dim3(16, 16, NB_), dim3(64, 4), 0, stream>>>(out_w, OWT);
    repack_qb<<<48, 256, 0, stream>>>(qkv_b, QBR);

    for (int layer = 0; layer < NB_; ++layer) {
        ln_kernel<<<M_, 256, 0, stream>>>(x, ln_g + layer * D_, ln_b + layer * D_, XN);
        gemm_nt<false><<<dim3(QN_ / 128, M_ / 128), 256, 0, stream>>>(
            XN, WT + (size_t)layer * QN_ * D_, QBR + layer * QN_, nullptr, QK, VT, D_, QKN_, 2048);
        vsum_kernel<<<1024, 256, 0, stream>>>(VT, VS);
        attn_kernel<<<1024, 256, 0, stream>>>(QK, VT, past_ids, VS, ATT);
        gemm_nt<true><<<dim3(D_ / 128, M_ / 128), 256, 0, stream>>>(
            ATT, OWT + (size_t)layer * D_ * D_, out_b + layer * D_, x, nullptr, nullptr, D_, D_, 1 << 30);
    }
}